// Round 1
// baseline (351.893 us; speedup 1.0000x reference)
//
#include <hip/hip_runtime.h>
#include <math.h>

#define HDIM 768
#define RDIM 64
#define NEXP 8
#define NTOK 16384

__device__ __forceinline__ float gelu_exact(float v) {
    return 0.5f * v * (1.0f + erff(v * 0.70710678118654752440f));
}

// ---------------------------------------------------------------------------
// Router: Xenc = x @ enc_w + enc_b (64-token x 64-R tile per block, K=768),
// epilogue: logits = Xenc @ sw_w + sw_b, softmax, top-1 -> pmax + expert lists
// ---------------------------------------------------------------------------
__global__ __launch_bounds__(256) void router_kernel(
    const float* __restrict__ x, const float* __restrict__ enc_w,
    const float* __restrict__ enc_b, const float* __restrict__ sw_w,
    const float* __restrict__ sw_b, float* __restrict__ pmax,
    int* __restrict__ counts, int* __restrict__ lists)
{
    __shared__ float xa[64][68];   // pad 68: 4-row strided reads land 2-way (free)
    __shared__ float wb[64][68];
    const int tid = threadIdx.x;
    const int tok0 = blockIdx.x * 64;
    const int ty = tid >> 4, tx = tid & 15;
    const int ty4 = ty * 4, tx4 = tx * 4;

    float acc[4][4] = {};

    for (int k0 = 0; k0 < HDIM; k0 += 64) {
        #pragma unroll
        for (int rr = 0; rr < 4; rr++) {
            int row = ty + rr * 16;
            *(float4*)&xa[row][tx4] =
                *(const float4*)(x + (size_t)(tok0 + row) * HDIM + k0 + tx4);
        }
        #pragma unroll
        for (int it = 0; it < 4; it++) {
            int off = it * 1024 + tid * 4;   // contiguous 64x64 slab of enc_w
            *(float4*)&wb[off >> 6][off & 63] =
                *(const float4*)(enc_w + (size_t)k0 * RDIM + off);
        }
        __syncthreads();
        #pragma unroll 8
        for (int kk = 0; kk < 64; kk++) {
            float4 b = *(float4*)&wb[kk][tx4];
            float a0 = xa[ty4 + 0][kk];
            float a1 = xa[ty4 + 1][kk];
            float a2 = xa[ty4 + 2][kk];
            float a3 = xa[ty4 + 3][kk];
            acc[0][0] += a0 * b.x; acc[0][1] += a0 * b.y; acc[0][2] += a0 * b.z; acc[0][3] += a0 * b.w;
            acc[1][0] += a1 * b.x; acc[1][1] += a1 * b.y; acc[1][2] += a1 * b.z; acc[1][3] += a1 * b.w;
            acc[2][0] += a2 * b.x; acc[2][1] += a2 * b.y; acc[2][2] += a2 * b.z; acc[2][3] += a2 * b.w;
            acc[3][0] += a3 * b.x; acc[3][1] += a3 * b.y; acc[3][2] += a3 * b.z; acc[3][3] += a3 * b.w;
        }
        __syncthreads();
    }

    // Xenc tile -> LDS (reuse xa)
    float eb[4];
    #pragma unroll
    for (int j = 0; j < 4; j++) eb[j] = enc_b[tx4 + j];
    #pragma unroll
    for (int i = 0; i < 4; i++) {
        #pragma unroll
        for (int j = 0; j < 4; j++)
            xa[ty4 + i][tx4 + j] = acc[i][j] + eb[j];
    }
    __syncthreads();

    if (tid < 64) {
        const int t = tid;
        float logit[NEXP];
        #pragma unroll
        for (int e = 0; e < NEXP; e++) logit[e] = sw_b[e];
        for (int r = 0; r < RDIM; r++) {
            float xe = xa[t][r];
            #pragma unroll
            for (int e = 0; e < NEXP; e++) logit[e] += xe * sw_w[r * NEXP + e];
        }
        // argmax with first-max tie rule (strict >) == jnp.argmax semantics
        float m = logit[0];
        int am = 0;
        #pragma unroll
        for (int e = 1; e < NEXP; e++) {
            if (logit[e] > m) { m = logit[e]; am = e; }
        }
        float s = 0.f;
        #pragma unroll
        for (int e = 0; e < NEXP; e++) s += expf(logit[e] - m);
        pmax[tok0 + t] = 1.0f / s;           // max prob = exp(m-m)/sum
        int pos = atomicAdd(&counts[am], 1);
        lists[am * NTOK + pos] = tok0 + t;
    }
}

// ---------------------------------------------------------------------------
// Expert: per-expert gathered 64-token tiles.
//   h  = gelu(Xg @ w1[e] + b1[e])      (M=64, N=64, K=768)
//   out = (h @ w2[e] + b2[e]) * pmax   (M=64, N=768, K=64), scattered rows
// ---------------------------------------------------------------------------
__global__ __launch_bounds__(256) void expert_kernel(
    const float* __restrict__ x, const float* __restrict__ w1,
    const float* __restrict__ b1, const float* __restrict__ w2,
    const float* __restrict__ b2, const float* __restrict__ pmax,
    const int* __restrict__ counts, const int* __restrict__ lists,
    float* __restrict__ out)
{
    __shared__ float xa[64][68];
    __shared__ float wb[64][68];
    __shared__ float hs[64][68];
    __shared__ int   tok_s[64];
    __shared__ float pm_s[64];

    const int tid = threadIdx.x;
    const int e = blockIdx.x;
    const int nTok = counts[e];
    const int ty = tid >> 4, tx = tid & 15;
    const int ty4 = ty * 4, tx4 = tx * 4;

    for (int tile = blockIdx.y; tile * 64 < nTok; tile += gridDim.y) {
        const int base = tile * 64;
        const int nt = min(64, nTok - base);
        if (tid < 64) {
            int idx = (tid < nt) ? tid : 0;     // pad slots with a valid token
            int tk = lists[e * NTOK + base + idx];
            tok_s[tid] = tk;
            pm_s[tid] = pmax[tk];
        }
        __syncthreads();

        // ---- matmul1: h = gelu(Xg @ w1[e] + b1[e]) ----
        float acc[4][4] = {};
        for (int k0 = 0; k0 < HDIM; k0 += 64) {
            #pragma unroll
            for (int rr = 0; rr < 4; rr++) {
                int row = ty + rr * 16;
                int tk = tok_s[row];
                *(float4*)&xa[row][tx4] =
                    *(const float4*)(x + (size_t)tk * HDIM + k0 + tx4);
            }
            #pragma unroll
            for (int it = 0; it < 4; it++) {
                int off = it * 1024 + tid * 4;   // contiguous 64x64 slab of w1[e]
                *(float4*)&wb[off >> 6][off & 63] =
                    *(const float4*)(w1 + ((size_t)e * HDIM + k0) * RDIM + off);
            }
            __syncthreads();
            #pragma unroll 8
            for (int kk = 0; kk < 64; kk++) {
                float4 b = *(float4*)&wb[kk][tx4];
                float a0 = xa[ty4 + 0][kk];
                float a1 = xa[ty4 + 1][kk];
                float a2 = xa[ty4 + 2][kk];
                float a3 = xa[ty4 + 3][kk];
                acc[0][0] += a0 * b.x; acc[0][1] += a0 * b.y; acc[0][2] += a0 * b.z; acc[0][3] += a0 * b.w;
                acc[1][0] += a1 * b.x; acc[1][1] += a1 * b.y; acc[1][2] += a1 * b.z; acc[1][3] += a1 * b.w;
                acc[2][0] += a2 * b.x; acc[2][1] += a2 * b.y; acc[2][2] += a2 * b.z; acc[2][3] += a2 * b.w;
                acc[3][0] += a3 * b.x; acc[3][1] += a3 * b.y; acc[3][2] += a3 * b.z; acc[3][3] += a3 * b.w;
            }
            __syncthreads();
        }
        {
            float b1v[4];
            #pragma unroll
            for (int j = 0; j < 4; j++) b1v[j] = b1[e * RDIM + tx4 + j];
            #pragma unroll
            for (int i = 0; i < 4; i++) {
                #pragma unroll
                for (int j = 0; j < 4; j++)
                    hs[ty4 + i][tx4 + j] = gelu_exact(acc[i][j] + b1v[j]);
            }
        }
        __syncthreads();

        // ---- matmul2: out = (h @ w2[e] + b2[e]) * pmax ----
        for (int n0 = 0; n0 < HDIM; n0 += 64) {
            #pragma unroll
            for (int rr = 0; rr < 4; rr++) {
                int row = ty + rr * 16;          // r index
                *(float4*)&wb[row][tx4] =
                    *(const float4*)(w2 + ((size_t)e * RDIM + row) * HDIM + n0 + tx4);
            }
            __syncthreads();

            float acc2[4][4] = {};
            #pragma unroll 8
            for (int kk = 0; kk < 64; kk++) {
                float4 b = *(float4*)&wb[kk][tx4];
                float a0 = hs[ty4 + 0][kk];
                float a1 = hs[ty4 + 1][kk];
                float a2 = hs[ty4 + 2][kk];
                float a3 = hs[ty4 + 3][kk];
                acc2[0][0] += a0 * b.x; acc2[0][1] += a0 * b.y; acc2[0][2] += a0 * b.z; acc2[0][3] += a0 * b.w;
                acc2[1][0] += a1 * b.x; acc2[1][1] += a1 * b.y; acc2[1][2] += a1 * b.z; acc2[1][3] += a1 * b.w;
                acc2[2][0] += a2 * b.x; acc2[2][1] += a2 * b.y; acc2[2][2] += a2 * b.z; acc2[2][3] += a2 * b.w;
                acc2[3][0] += a3 * b.x; acc2[3][1] += a3 * b.y; acc2[3][2] += a3 * b.z; acc2[3][3] += a3 * b.w;
            }

            float4 b2v = *(const float4*)(b2 + (size_t)e * HDIM + n0 + tx4);
            #pragma unroll
            for (int i = 0; i < 4; i++) {
                int slot = ty4 + i;
                if (slot < nt) {
                    int tk = tok_s[slot];
                    float pm = pm_s[slot];
                    float4 o;
                    o.x = (acc2[i][0] + b2v.x) * pm;
                    o.y = (acc2[i][1] + b2v.y) * pm;
                    o.z = (acc2[i][2] + b2v.z) * pm;
                    o.w = (acc2[i][3] + b2v.w) * pm;
                    *(float4*)(out + (size_t)tk * HDIM + n0 + tx4) = o;
                }
            }
            __syncthreads();
        }
    }
}

extern "C" void kernel_launch(void* const* d_in, const int* in_sizes, int n_in,
                              void* d_out, int out_size, void* d_ws, size_t ws_size,
                              hipStream_t stream) {
    const float* x     = (const float*)d_in[0];
    const float* enc_w = (const float*)d_in[1];
    const float* enc_b = (const float*)d_in[2];
    const float* sw_w  = (const float*)d_in[3];
    const float* sw_b  = (const float*)d_in[4];
    const float* w1    = (const float*)d_in[5];
    const float* b1    = (const float*)d_in[6];
    const float* w2    = (const float*)d_in[7];
    const float* b2    = (const float*)d_in[8];
    float* out = (float*)d_out;

    // Workspace layout: [counts: 8 ints (zeroed)] [pad to 256B]
    //                   [pmax: 16384 f32] [lists: 8*16384 i32]  (~590 KB)
    int*   counts = (int*)d_ws;
    float* pmax   = (float*)((char*)d_ws + 256);
    int*   lists  = (int*)((char*)d_ws + 256 + NTOK * sizeof(float));

    hipMemsetAsync(d_ws, 0, 256, stream);   // zero atomic counters (ws is re-poisoned each call)

    hipLaunchKernelGGL(router_kernel, dim3(NTOK / 64), dim3(256), 0, stream,
                       x, enc_w, enc_b, sw_w, sw_b, pmax, counts, lists);
    hipLaunchKernelGGL(expert_kernel, dim3(NEXP, 32), dim3(256), 0, stream,
                       x, w1, b1, w2, b2, pmax, counts, lists, out);
}